// Round 19
// baseline (142.512 us; speedup 1.0000x reference)
//
#include <hip/hip_runtime.h>
#include <cstdint>
#include <cstddef>

// ---------- constants for this problem ----------
#define BATCH 2
#define SEQ   2048
#define HID   1024
#define NHEAD 16
#define DHEAD 64
#define QKV_N 3072   // 3*HID
#define NTOK  4096   // BATCH*SEQ

typedef __attribute__((ext_vector_type(4))) float f32x4;
typedef __attribute__((ext_vector_type(8))) short bf16x8;

#define QSCL 0.18033688011112042f   // (1/8) * log2(e), folded into Q at GEMM epilogue

__device__ inline unsigned short f2bf(float f) {
    union { float f; unsigned int u; } v; v.f = f;
    unsigned int u = v.u;
    unsigned int r = (u + 0x7fffu + ((u >> 16) & 1u)) >> 16;
    return (unsigned short)r;
}

// pack two positive floats to bf16 pair (round-half-up): P in [0,1], no NaN/inf.
__device__ __forceinline__ unsigned int pack_bf16_rh(float a, float b) {
    union { float f; unsigned int u; } ua, ub;
    ua.f = a; ub.f = b;
    return ((ua.u + 0x8000u) >> 16) | ((ub.u + 0x8000u) & 0xffff0000u);
}

__device__ __forceinline__ void gload_lds16(const void* g, void* l) {
    __builtin_amdgcn_global_load_lds(
        (const __attribute__((address_space(1))) void*)g,
        (__attribute__((address_space(3))) void*)l, 16, 0, 0);
}

// ---------- fused cast fp32 -> bf16 for x, W_qkv, W_o (one launch) ----------
#define N1 (NTOK * HID / 4)     // x:     1,048,576 float4
#define N2 (QKV_N * HID / 4)    // W_qkv:   786,432
#define N3 (HID * HID / 4)      // W_o:     262,144

__global__ __launch_bounds__(256) void cast3_f32_bf16(const float* __restrict__ x,
                                                      const float* __restrict__ wqkv,
                                                      const float* __restrict__ wo,
                                                      unsigned short* __restrict__ xb,
                                                      unsigned short* __restrict__ wqkvb,
                                                      unsigned short* __restrict__ wob) {
    int i = blockIdx.x * blockDim.x + threadIdx.x;
    const float* src;
    unsigned short* dst;
    int k;
    if (i < N1)            { src = x;    dst = xb;    k = i; }
    else if (i < N1 + N2)  { src = wqkv; dst = wqkvb; k = i - N1; }
    else                   { src = wo;   dst = wob;   k = i - N1 - N2; }
    float4 v = reinterpret_cast<const float4*>(src)[k];
    ushort4 o;
    o.x = f2bf(v.x); o.y = f2bf(v.y); o.z = f2bf(v.z); o.w = f2bf(v.w);
    reinterpret_cast<ushort4*>(dst)[k] = o;
}

// ---------- GEMM, 2-phase dbuf pipeline, BK=32 (R5/R13 verified structure) ----------
// R19: qkv uses BN=256 (NJ=8 -> 32 MFMA/wave per barrier interval, m93 lever).
template<int BN, int OUT_MODE>
__global__ __launch_bounds__(256) void gemm_bt(const short* __restrict__ A,
                                               const short* __restrict__ B,
                                               const float* __restrict__ bias,
                                               void* __restrict__ Cout,
                                               int M, int N, int K) {
    constexpr int WTN = BN / 2;
    constexpr int NJ  = WTN / 16;
    constexpr int NBC = BN / 64;

    __shared__ short sA[2][128 * 32];
    __shared__ short sB[2][BN * 32];

    const int tid  = threadIdx.x;
    const int lane = tid & 63;
    const int wave = tid >> 6;
    const int wm = wave >> 1, wn = wave & 1;

    const int nwg = gridDim.x;
    const int swz = (blockIdx.x & 7) * (nwg >> 3) + (blockIdx.x >> 3);
    const int tiles_n = N / BN;
    const int m0 = (swz / tiles_n) * 128;
    const int n0 = (swz % tiles_n) * BN;

    f32x4 acc[4][NJ];
    #pragma unroll
    for (int i = 0; i < 4; ++i)
        #pragma unroll
        for (int j = 0; j < NJ; ++j) acc[i][j] = (f32x4){0.f, 0.f, 0.f, 0.f};

    const int r = lane & 15;
    const int G = lane >> 4;

    #define GSTAGE(kt_, buf_)                                                          \
        {                                                                              \
            _Pragma("unroll")                                                          \
            for (int i = 0; i < 2; ++i) {                                              \
                int ga = (i * 4 + wave) * 64 + lane;                                   \
                int row = ga >> 2, gcol = (ga & 3) ^ (row & 3);                        \
                gload_lds16(A + (size_t)(m0 + row) * K + (kt_) + gcol * 8,             \
                            &sA[buf_][(i * 4 + wave) * 512]);                          \
            }                                                                          \
            _Pragma("unroll")                                                          \
            for (int i = 0; i < NBC; ++i) {                                            \
                int gb = (i * 4 + wave) * 64 + lane;                                   \
                int row = gb >> 2, gcol = (gb & 3) ^ (row & 3);                        \
                gload_lds16(B + (size_t)(n0 + row) * K + (kt_) + gcol * 8,             \
                            &sB[buf_][(i * 4 + wave) * 512]);                          \
            }                                                                          \
        }

    GSTAGE(0, 0);
    __syncthreads();
    int cur = 0;

    const int nsteps = K >> 5;
    for (int ks = 0; ks < nsteps; ++ks) {
        if (ks + 1 < nsteps) GSTAGE((ks + 1) * 32, cur ^ 1);

        const int sg = G ^ (r & 3);
        bf16x8 af[4], bfr[NJ];
        #pragma unroll
        for (int i = 0; i < 4; ++i) {
            int row = wm * 64 + i * 16 + r;
            af[i] = *reinterpret_cast<const bf16x8*>(&sA[cur][row * 32 + sg * 8]);
        }
        #pragma unroll
        for (int j = 0; j < NJ; ++j) {
            int row = wn * WTN + j * 16 + r;
            bfr[j] = *reinterpret_cast<const bf16x8*>(&sB[cur][row * 32 + sg * 8]);
        }
        #pragma unroll
        for (int i = 0; i < 4; ++i)
            #pragma unroll
            for (int j = 0; j < NJ; ++j)
                acc[i][j] = __builtin_amdgcn_mfma_f32_16x16x32_bf16(af[i], bfr[j], acc[i][j], 0, 0, 0);

        __syncthreads();
        cur ^= 1;
    }
    #undef GSTAGE

    const int col_l = lane & 15;
    const int row_g = (lane >> 4) * 4;
    #pragma unroll
    for (int i = 0; i < 4; ++i) {
        #pragma unroll
        for (int j = 0; j < NJ; ++j) {
            int nn = n0 + wn * WTN + j * 16 + col_l;
            float bv = bias[nn];
            float scl = (OUT_MODE == 2 && nn < HID) ? QSCL : 1.0f;
            #pragma unroll
            for (int reg = 0; reg < 4; ++reg) {
                int mm = m0 + wm * 64 + i * 16 + row_g + reg;
                float v = (acc[i][j][reg] + bv) * scl;
                if (OUT_MODE == 0) {
                    reinterpret_cast<float*>(Cout)[(size_t)mm * N + nn] = v;
                } else {
                    reinterpret_cast<unsigned short*>(Cout)[(size_t)mm * N + nn] = f2bf(v);
                }
            }
        }
    }
}

// ---------- transpose V part of qkv -> vP [bh][T][d][j] (PV-fragment order) ----------
// (unchanged from R11 -- verified)
#define TLDP 72
__global__ __launch_bounds__(256) void transpose_v(const short* __restrict__ qkv,
                                                   short* __restrict__ vP) {
    const int st = blockIdx.x;
    const int bh = blockIdx.y;
    const int b  = bh >> 4, h = bh & 15;
    __shared__ short ld[64 * TLDP];
    const int tid = threadIdx.x;

    #pragma unroll
    for (int i = 0; i < 2; ++i) {
        int idx = i * 256 + tid;
        int row = idx >> 3, c = idx & 7;
        int4 v = *reinterpret_cast<const int4*>(
            qkv + ((size_t)(b * SEQ + st * 64 + row)) * QKV_N + 2 * HID + h * DHEAD + c * 8);
        *reinterpret_cast<int4*>(&ld[row * TLDP + c * 8]) = v;
    }
    __syncthreads();
    #pragma unroll
    for (int i = 0; i < 2; ++i) {
        int u  = i * 256 + tid;
        int Tp = u >> 8;
        int d  = (u >> 2) & 63;
        int p  = u & 3;
        int b0 = Tp * 32 + 4 * p;
        int b1 = b0 + 16;
        ushort4 o0, o1;
        o0.x = (unsigned short)ld[(b0 + 0) * TLDP + d];
        o0.y = (unsigned short)ld[(b0 + 1) * TLDP + d];
        o0.z = (unsigned short)ld[(b0 + 2) * TLDP + d];
        o0.w = (unsigned short)ld[(b0 + 3) * TLDP + d];
        o1.x = (unsigned short)ld[(b1 + 0) * TLDP + d];
        o1.y = (unsigned short)ld[(b1 + 1) * TLDP + d];
        o1.z = (unsigned short)ld[(b1 + 2) * TLDP + d];
        o1.w = (unsigned short)ld[(b1 + 3) * TLDP + d];
        size_t out = ((size_t)((bh * 64 + st * 2 + Tp) * 64 + d)) * 32 + p * 8;
        *reinterpret_cast<ushort4*>(&vP[out])     = o0;
        *reinterpret_cast<ushort4*>(&vP[out + 4]) = o1;
    }
}

// ---------- flash attention (causal): R13 verified body + R13 qb map (reverted) ----------
__global__ __launch_bounds__(256) void attn_fwd(const short* __restrict__ qkv,
                                                const short* __restrict__ vP,
                                                short* __restrict__ av) {
    const int bid = blockIdx.x;
    const int qb  = 31 - (bid >> 5);     // 0..31, heaviest blocks dispatched first
    const int bh  = bid & 31;            // bid%8 == bh%8 -> per-head XCD affinity
    const int b   = bh >> 4;
    const int h   = bh & 15;

    __shared__ float comb[64][68];       // cols 0..63 = O[q][d], col 64 = L[q]

    const int tid  = threadIdx.x;
    const int lane = tid & 63;
    const int wave = tid >> 6;           // 0..3 (kv-split)
    const int r    = lane & 15;
    const int G    = lane >> 4;
    const int row_g = G * 4;

    const int qbw = qb * 64;             // first q row of this block

    // Q fragments for 4 mi (pre-scaled by QSCL); B-frag: col = q = r, k = d
    bf16x8 qf[4][2];
    #pragma unroll
    for (int mi = 0; mi < 4; ++mi) {
        const short* Qg = qkv + ((size_t)(b * SEQ + qbw + mi * 16 + r)) * QKV_N + h * DHEAD;
        qf[mi][0] = *reinterpret_cast<const bf16x8*>(Qg + G * 8);
        qf[mi][1] = *reinterpret_cast<const bf16x8*>(Qg + 32 + G * 8);
    }

    f32x4 oacc[4][4];
    f32x4 oL[4];
    #pragma unroll
    for (int mi = 0; mi < 4; ++mi) {
        oL[mi] = (f32x4){0.f, 0.f, 0.f, 0.f};
        #pragma unroll
        for (int dg = 0; dg < 4; ++dg) oacc[mi][dg] = (f32x4){0.f, 0.f, 0.f, 0.f};
    }

    bf16x8 ones;
    #pragma unroll
    for (int e = 0; e < 8; ++e) ones[e] = (short)0x3f80;   // bf16 1.0

    // per-lane base pointers (strength-reduced: incremented each iteration)
    const short* kpt = qkv + (size_t)(b * SEQ + wave * 32) * QKV_N + HID + h * DHEAD
                       + r * QKV_N + G * 8;
    const short* vpt = vP + (size_t)(bh * 64 + wave) * 2048 + r * 32 + G * 8;
    const ptrdiff_t KSTEP = (ptrdiff_t)128 * QKV_N;
    const ptrdiff_t VSTEP = 4 * 2048;
    const int KG1 = 16 * QKV_N;

    const int tlast = 2 * qb + 1;
    for (int t = wave; t <= tlast; t += 4) {
        int4 k00 = *reinterpret_cast<const int4*>(kpt);
        int4 k01 = *reinterpret_cast<const int4*>(kpt + 32);
        int4 k10 = *reinterpret_cast<const int4*>(kpt + KG1);
        int4 k11 = *reinterpret_cast<const int4*>(kpt + KG1 + 32);
        int4 v0 = *reinterpret_cast<const int4*>(vpt);
        int4 v1 = *reinterpret_cast<const int4*>(vpt + 16 * 32);
        int4 v2 = *reinterpret_cast<const int4*>(vpt + 32 * 32);
        int4 v3 = *reinterpret_cast<const int4*>(vpt + 48 * 32);
        kpt += KSTEP;
        vpt += VSTEP;

        bf16x8 kb[2][2], vb[4];
        __builtin_memcpy(&kb[0][0], &k00, 16);
        __builtin_memcpy(&kb[0][1], &k01, 16);
        __builtin_memcpy(&kb[1][0], &k10, 16);
        __builtin_memcpy(&kb[1][1], &k11, 16);
        __builtin_memcpy(&vb[0], &v0, 16);
        __builtin_memcpy(&vb[1], &v1, 16);
        __builtin_memcpy(&vb[2], &v2, 16);
        __builtin_memcpy(&vb[3], &v3, 16);

        const bool band = (t >= 2 * qb);

        #pragma unroll
        for (int mi = 0; mi < 4; ++mi) {
            f32x4 s[2];
            #pragma unroll
            for (int g = 0; g < 2; ++g) {
                f32x4 z = (f32x4){0.f, 0.f, 0.f, 0.f};
                z = __builtin_amdgcn_mfma_f32_16x16x32_bf16(kb[g][0], qf[mi][0], z, 0, 0, 0);
                z = __builtin_amdgcn_mfma_f32_16x16x32_bf16(kb[g][1], qf[mi][1], z, 0, 0, 0);
                s[g] = z;
            }
            if (band) {
                int qg = qbw + mi * 16 + r;
                #pragma unroll
                for (int g = 0; g < 2; ++g) {
                    #pragma unroll
                    for (int reg = 0; reg < 4; ++reg) {
                        int kvg = t * 32 + g * 16 + row_g + reg;
                        if (kvg > qg) s[g][reg] = -30000.f;
                    }
                }
            }
            float p0 = __builtin_amdgcn_exp2f(s[0][0]);
            float p1 = __builtin_amdgcn_exp2f(s[0][1]);
            float p2 = __builtin_amdgcn_exp2f(s[0][2]);
            float p3 = __builtin_amdgcn_exp2f(s[0][3]);
            float p4 = __builtin_amdgcn_exp2f(s[1][0]);
            float p5 = __builtin_amdgcn_exp2f(s[1][1]);
            float p6 = __builtin_amdgcn_exp2f(s[1][2]);
            float p7 = __builtin_amdgcn_exp2f(s[1][3]);
            unsigned int w0 = pack_bf16_rh(p0, p1);
            unsigned int w1 = pack_bf16_rh(p2, p3);
            unsigned int w2 = pack_bf16_rh(p4, p5);
            unsigned int w3 = pack_bf16_rh(p6, p7);
            bf16x8 pb;
            { int4 f; f.x = (int)w0; f.y = (int)w1; f.z = (int)w2; f.w = (int)w3;
              __builtin_memcpy(&pb, &f, 16); }

            #pragma unroll
            for (int dg = 0; dg < 4; ++dg)
                oacc[mi][dg] = __builtin_amdgcn_mfma_f32_16x16x32_bf16(vb[dg], pb, oacc[mi][dg], 0, 0, 0);
            oL[mi] = __builtin_amdgcn_mfma_f32_16x16x32_bf16(ones, pb, oL[mi], 0, 0, 0);
        }
    }

    // ---- combine (pure sums over kv, no-max softmax): 3-barrier serial LDS add ----
    __syncthreads();
    if (wave == 0) {
        #pragma unroll
        for (int mi = 0; mi < 4; ++mi) {
            #pragma unroll
            for (int dg = 0; dg < 4; ++dg)
                *reinterpret_cast<f32x4*>(&comb[mi * 16 + r][dg * 16 + row_g]) = oacc[mi][dg];
            if (G == 0) comb[mi * 16 + r][64] = oL[mi][0];
        }
    }
    __syncthreads();
    if (wave == 1) {
        #pragma unroll
        for (int mi = 0; mi < 4; ++mi) {
            #pragma unroll
            for (int dg = 0; dg < 4; ++dg) {
                f32x4 c = *reinterpret_cast<f32x4*>(&comb[mi * 16 + r][dg * 16 + row_g]);
                *reinterpret_cast<f32x4*>(&comb[mi * 16 + r][dg * 16 + row_g]) = c + oacc[mi][dg];
            }
            if (G == 0) comb[mi * 16 + r][64] += oL[mi][0];
        }
    }
    __syncthreads();
    if (wave == 2) {
        #pragma unroll
        for (int mi = 0; mi < 4; ++mi) {
            #pragma unroll
            for (int dg = 0; dg < 4; ++dg) {
                f32x4 c = *reinterpret_cast<f32x4*>(&comb[mi * 16 + r][dg * 16 + row_g]);
                *reinterpret_cast<f32x4*>(&comb[mi * 16 + r][dg * 16 + row_g]) = c + oacc[mi][dg];
            }
            if (G == 0) comb[mi * 16 + r][64] += oL[mi][0];
        }
    }
    __syncthreads();
    if (wave == 3) {
        #pragma unroll
        for (int mi = 0; mi < 4; ++mi) {
            float l = comb[mi * 16 + r][64] + oL[mi][0];
            float il = 1.0f / l;
            size_t tok = (size_t)(b * SEQ + qbw + mi * 16 + r);
            #pragma unroll
            for (int dg = 0; dg < 4; ++dg) {
                f32x4 tot = *reinterpret_cast<f32x4*>(&comb[mi * 16 + r][dg * 16 + row_g]);
                tot = tot + oacc[mi][dg];
                ushort4 o;
                o.x = f2bf(tot[0] * il);
                o.y = f2bf(tot[1] * il);
                o.z = f2bf(tot[2] * il);
                o.w = f2bf(tot[3] * il);
                *reinterpret_cast<ushort4*>(&av[tok * HID + h * DHEAD + dg * 16 + row_g]) = o;
            }
        }
    }
}

extern "C" void kernel_launch(void* const* d_in, const int* in_sizes, int n_in,
                              void* d_out, int out_size, void* d_ws, size_t ws_size,
                              hipStream_t stream) {
    const float* x     = (const float*)d_in[0];
    const float* W_qkv = (const float*)d_in[1];
    const float* b_qkv = (const float*)d_in[2];
    const float* W_o   = (const float*)d_in[3];
    const float* b_o   = (const float*)d_in[4];
    float* out = (float*)d_out;

    const int n_x    = NTOK * HID;
    const int n_wqkv = QKV_N * HID;
    const int n_wo   = HID * HID;
    const int n_qkv  = NTOK * QKV_N;
    const int n_av   = NTOK * HID;

    short* xb    = (short*)d_ws;
    short* wqkvb = xb + n_x;
    short* wob   = wqkvb + n_wqkv;
    short* qkv   = wob + n_wo;
    short* av    = qkv + n_qkv;
    short* vP    = av + n_av;

    // fused cast: x, W_qkv, W_o in ONE launch
    cast3_f32_bf16<<<(N1 + N2 + N3) / 256, 256, 0, stream>>>(
        x, W_qkv, W_o, (unsigned short*)xb, (unsigned short*)wqkvb, (unsigned short*)wob);

    // qkv = x @ W_qkv^T + b_qkv  -> bf16 [4096][3072]; BN=256 tile (32 MFMA/barrier)
    gemm_bt<256, 2><<<(NTOK / 128) * (QKV_N / 256), 256, 0, stream>>>(
        xb, wqkvb, b_qkv, (void*)qkv, NTOK, QKV_N, HID);

    // vP [32 bh][64 T][64 d][32 j] (PV-fragment order)
    transpose_v<<<dim3(SEQ / 64, BATCH * NHEAD), 256, 0, stream>>>(qkv, vP);

    // attention -> av bf16 [4096][1024]; R13 verified (1024 blocks x 4 waves)
    attn_fwd<<<1024, 256, 0, stream>>>(qkv, vP, av);

    // out = av @ W_o^T + b_o  -> fp32
    gemm_bt<64, 0><<<(NTOK / 128) * (HID / 64), 256, 0, stream>>>(
        av, wob, b_o, (void*)out, NTOK, HID, HID);
}

// Round 20
// 111.525 us; speedup vs baseline: 1.2779x; 1.2779x over previous
//
#include <hip/hip_runtime.h>
#include <cstdint>
#include <cstddef>

// ---------- constants for this problem ----------
#define BATCH 2
#define SEQ   2048
#define HID   1024
#define NHEAD 16
#define DHEAD 64
#define QKV_N 3072   // 3*HID
#define NTOK  4096   // BATCH*SEQ

typedef __attribute__((ext_vector_type(4))) float f32x4;
typedef __attribute__((ext_vector_type(8))) short bf16x8;

#define QSCL 0.18033688011112042f   // (1/8) * log2(e), folded into Q at GEMM epilogue

__device__ inline unsigned short f2bf(float f) {
    union { float f; unsigned int u; } v; v.f = f;
    unsigned int u = v.u;
    unsigned int r = (u + 0x7fffu + ((u >> 16) & 1u)) >> 16;
    return (unsigned short)r;
}

// pack two positive floats to bf16 pair (round-half-up): P in [0,1], no NaN/inf.
__device__ __forceinline__ unsigned int pack_bf16_rh(float a, float b) {
    union { float f; unsigned int u; } ua, ub;
    ua.f = a; ub.f = b;
    return ((ua.u + 0x8000u) >> 16) | ((ub.u + 0x8000u) & 0xffff0000u);
}

__device__ __forceinline__ void gload_lds16(const void* g, void* l) {
    __builtin_amdgcn_global_load_lds(
        (const __attribute__((address_space(1))) void*)g,
        (__attribute__((address_space(3))) void*)l, 16, 0, 0);
}

// ---------- fused cast fp32 -> bf16 for x, W_qkv, W_o (one launch; R18 verified) ----------
#define N1 (NTOK * HID / 4)     // x:     1,048,576 float4
#define N2 (QKV_N * HID / 4)    // W_qkv:   786,432
#define N3 (HID * HID / 4)      // W_o:     262,144

__global__ __launch_bounds__(256) void cast3_f32_bf16(const float* __restrict__ x,
                                                      const float* __restrict__ wqkv,
                                                      const float* __restrict__ wo,
                                                      unsigned short* __restrict__ xb,
                                                      unsigned short* __restrict__ wqkvb,
                                                      unsigned short* __restrict__ wob) {
    int i = blockIdx.x * blockDim.x + threadIdx.x;
    const float* src;
    unsigned short* dst;
    int k;
    if (i < N1)            { src = x;    dst = xb;    k = i; }
    else if (i < N1 + N2)  { src = wqkv; dst = wqkvb; k = i - N1; }
    else                   { src = wo;   dst = wob;   k = i - N1 - N2; }
    float4 v = reinterpret_cast<const float4*>(src)[k];
    ushort4 o;
    o.x = f2bf(v.x); o.y = f2bf(v.y); o.z = f2bf(v.z); o.w = f2bf(v.w);
    reinterpret_cast<ushort4*>(dst)[k] = o;
}

// ---------- GEMM, 2-phase dbuf pipeline, BK=32, BN=128/64 (R5/R13 verified) ----------
template<int BN, int OUT_MODE>
__global__ __launch_bounds__(256) void gemm_bt(const short* __restrict__ A,
                                               const short* __restrict__ B,
                                               const float* __restrict__ bias,
                                               void* __restrict__ Cout,
                                               int M, int N, int K) {
    constexpr int WTN = BN / 2;
    constexpr int NJ  = WTN / 16;
    constexpr int NBC = BN / 64;

    __shared__ short sA[2][128 * 32];
    __shared__ short sB[2][BN * 32];

    const int tid  = threadIdx.x;
    const int lane = tid & 63;
    const int wave = tid >> 6;
    const int wm = wave >> 1, wn = wave & 1;

    const int nwg = gridDim.x;
    const int swz = (blockIdx.x & 7) * (nwg >> 3) + (blockIdx.x >> 3);
    const int tiles_n = N / BN;
    const int m0 = (swz / tiles_n) * 128;
    const int n0 = (swz % tiles_n) * BN;

    f32x4 acc[4][NJ];
    #pragma unroll
    for (int i = 0; i < 4; ++i)
        #pragma unroll
        for (int j = 0; j < NJ; ++j) acc[i][j] = (f32x4){0.f, 0.f, 0.f, 0.f};

    const int r = lane & 15;
    const int G = lane >> 4;

    #define GSTAGE(kt_, buf_)                                                          \
        {                                                                              \
            _Pragma("unroll")                                                          \
            for (int i = 0; i < 2; ++i) {                                              \
                int ga = (i * 4 + wave) * 64 + lane;                                   \
                int row = ga >> 2, gcol = (ga & 3) ^ (row & 3);                        \
                gload_lds16(A + (size_t)(m0 + row) * K + (kt_) + gcol * 8,             \
                            &sA[buf_][(i * 4 + wave) * 512]);                          \
            }                                                                          \
            _Pragma("unroll")                                                          \
            for (int i = 0; i < NBC; ++i) {                                            \
                int gb = (i * 4 + wave) * 64 + lane;                                   \
                int row = gb >> 2, gcol = (gb & 3) ^ (row & 3);                        \
                gload_lds16(B + (size_t)(n0 + row) * K + (kt_) + gcol * 8,             \
                            &sB[buf_][(i * 4 + wave) * 512]);                          \
            }                                                                          \
        }

    GSTAGE(0, 0);
    __syncthreads();
    int cur = 0;

    const int nsteps = K >> 5;
    for (int ks = 0; ks < nsteps; ++ks) {
        if (ks + 1 < nsteps) GSTAGE((ks + 1) * 32, cur ^ 1);

        const int sg = G ^ (r & 3);
        bf16x8 af[4], bfr[NJ];
        #pragma unroll
        for (int i = 0; i < 4; ++i) {
            int row = wm * 64 + i * 16 + r;
            af[i] = *reinterpret_cast<const bf16x8*>(&sA[cur][row * 32 + sg * 8]);
        }
        #pragma unroll
        for (int j = 0; j < NJ; ++j) {
            int row = wn * WTN + j * 16 + r;
            bfr[j] = *reinterpret_cast<const bf16x8*>(&sB[cur][row * 32 + sg * 8]);
        }
        #pragma unroll
        for (int i = 0; i < 4; ++i)
            #pragma unroll
            for (int j = 0; j < NJ; ++j)
                acc[i][j] = __builtin_amdgcn_mfma_f32_16x16x32_bf16(af[i], bfr[j], acc[i][j], 0, 0, 0);

        __syncthreads();
        cur ^= 1;
    }
    #undef GSTAGE

    const int col_l = lane & 15;
    const int row_g = (lane >> 4) * 4;
    #pragma unroll
    for (int i = 0; i < 4; ++i) {
        #pragma unroll
        for (int j = 0; j < NJ; ++j) {
            int nn = n0 + wn * WTN + j * 16 + col_l;
            float bv = bias[nn];
            float scl = (OUT_MODE == 2 && nn < HID) ? QSCL : 1.0f;
            #pragma unroll
            for (int reg = 0; reg < 4; ++reg) {
                int mm = m0 + wm * 64 + i * 16 + row_g + reg;
                float v = (acc[i][j][reg] + bv) * scl;
                if (OUT_MODE == 0) {
                    reinterpret_cast<float*>(Cout)[(size_t)mm * N + nn] = v;
                } else {
                    reinterpret_cast<unsigned short*>(Cout)[(size_t)mm * N + nn] = f2bf(v);
                }
            }
        }
    }
}

// ---------- transpose V part of qkv -> vP [bh][T][d][j] (PV-fragment order) ----------
// (unchanged from R11 -- verified)
#define TLDP 72
__global__ __launch_bounds__(256) void transpose_v(const short* __restrict__ qkv,
                                                   short* __restrict__ vP) {
    const int st = blockIdx.x;
    const int bh = blockIdx.y;
    const int b  = bh >> 4, h = bh & 15;
    __shared__ short ld[64 * TLDP];
    const int tid = threadIdx.x;

    #pragma unroll
    for (int i = 0; i < 2; ++i) {
        int idx = i * 256 + tid;
        int row = idx >> 3, c = idx & 7;
        int4 v = *reinterpret_cast<const int4*>(
            qkv + ((size_t)(b * SEQ + st * 64 + row)) * QKV_N + 2 * HID + h * DHEAD + c * 8);
        *reinterpret_cast<int4*>(&ld[row * TLDP + c * 8]) = v;
    }
    __syncthreads();
    #pragma unroll
    for (int i = 0; i < 2; ++i) {
        int u  = i * 256 + tid;
        int Tp = u >> 8;
        int d  = (u >> 2) & 63;
        int p  = u & 3;
        int b0 = Tp * 32 + 4 * p;
        int b1 = b0 + 16;
        ushort4 o0, o1;
        o0.x = (unsigned short)ld[(b0 + 0) * TLDP + d];
        o0.y = (unsigned short)ld[(b0 + 1) * TLDP + d];
        o0.z = (unsigned short)ld[(b0 + 2) * TLDP + d];
        o0.w = (unsigned short)ld[(b0 + 3) * TLDP + d];
        o1.x = (unsigned short)ld[(b1 + 0) * TLDP + d];
        o1.y = (unsigned short)ld[(b1 + 1) * TLDP + d];
        o1.z = (unsigned short)ld[(b1 + 2) * TLDP + d];
        o1.w = (unsigned short)ld[(b1 + 3) * TLDP + d];
        size_t out = ((size_t)((bh * 64 + st * 2 + Tp) * 64 + d)) * 32 + p * 8;
        *reinterpret_cast<ushort4*>(&vP[out])     = o0;
        *reinterpret_cast<ushort4*>(&vP[out + 4]) = o1;
    }
}

// ---------- flash attention (causal): R13 byte-exact (best verified, 48.2 us) ----------
__global__ __launch_bounds__(256) void attn_fwd(const short* __restrict__ qkv,
                                                const short* __restrict__ vP,
                                                short* __restrict__ av) {
    const int bid = blockIdx.x;
    const int qb  = 31 - (bid >> 5);     // 0..31, heaviest blocks dispatched first
    const int bh  = bid & 31;            // bid%8 == bh%8 -> per-head XCD affinity
    const int b   = bh >> 4;
    const int h   = bh & 15;

    __shared__ float comb[64][68];       // cols 0..63 = O[q][d], col 64 = L[q]

    const int tid  = threadIdx.x;
    const int lane = tid & 63;
    const int wave = tid >> 6;           // 0..3 (kv-split)
    const int r    = lane & 15;
    const int G    = lane >> 4;
    const int row_g = G * 4;

    const int qbw = qb * 64;             // first q row of this block

    // Q fragments for 4 mi (pre-scaled by QSCL); B-frag: col = q = r, k = d
    bf16x8 qf[4][2];
    #pragma unroll
    for (int mi = 0; mi < 4; ++mi) {
        const short* Qg = qkv + ((size_t)(b * SEQ + qbw + mi * 16 + r)) * QKV_N + h * DHEAD;
        qf[mi][0] = *reinterpret_cast<const bf16x8*>(Qg + G * 8);
        qf[mi][1] = *reinterpret_cast<const bf16x8*>(Qg + 32 + G * 8);
    }

    f32x4 oacc[4][4];
    f32x4 oL[4];
    #pragma unroll
    for (int mi = 0; mi < 4; ++mi) {
        oL[mi] = (f32x4){0.f, 0.f, 0.f, 0.f};
        #pragma unroll
        for (int dg = 0; dg < 4; ++dg) oacc[mi][dg] = (f32x4){0.f, 0.f, 0.f, 0.f};
    }

    bf16x8 ones;
    #pragma unroll
    for (int e = 0; e < 8; ++e) ones[e] = (short)0x3f80;   // bf16 1.0

    // per-lane base pointers (strength-reduced: incremented each iteration)
    const short* kpt = qkv + (size_t)(b * SEQ + wave * 32) * QKV_N + HID + h * DHEAD
                       + r * QKV_N + G * 8;
    const short* vpt = vP + (size_t)(bh * 64 + wave) * 2048 + r * 32 + G * 8;
    const ptrdiff_t KSTEP = (ptrdiff_t)128 * QKV_N;
    const ptrdiff_t VSTEP = 4 * 2048;
    const int KG1 = 16 * QKV_N;

    const int tlast = 2 * qb + 1;
    for (int t = wave; t <= tlast; t += 4) {
        int4 k00 = *reinterpret_cast<const int4*>(kpt);
        int4 k01 = *reinterpret_cast<const int4*>(kpt + 32);
        int4 k10 = *reinterpret_cast<const int4*>(kpt + KG1);
        int4 k11 = *reinterpret_cast<const int4*>(kpt + KG1 + 32);
        int4 v0 = *reinterpret_cast<const int4*>(vpt);
        int4 v1 = *reinterpret_cast<const int4*>(vpt + 16 * 32);
        int4 v2 = *reinterpret_cast<const int4*>(vpt + 32 * 32);
        int4 v3 = *reinterpret_cast<const int4*>(vpt + 48 * 32);
        kpt += KSTEP;
        vpt += VSTEP;

        bf16x8 kb[2][2], vb[4];
        __builtin_memcpy(&kb[0][0], &k00, 16);
        __builtin_memcpy(&kb[0][1], &k01, 16);
        __builtin_memcpy(&kb[1][0], &k10, 16);
        __builtin_memcpy(&kb[1][1], &k11, 16);
        __builtin_memcpy(&vb[0], &v0, 16);
        __builtin_memcpy(&vb[1], &v1, 16);
        __builtin_memcpy(&vb[2], &v2, 16);
        __builtin_memcpy(&vb[3], &v3, 16);

        const bool band = (t >= 2 * qb);

        #pragma unroll
        for (int mi = 0; mi < 4; ++mi) {
            f32x4 s[2];
            #pragma unroll
            for (int g = 0; g < 2; ++g) {
                f32x4 z = (f32x4){0.f, 0.f, 0.f, 0.f};
                z = __builtin_amdgcn_mfma_f32_16x16x32_bf16(kb[g][0], qf[mi][0], z, 0, 0, 0);
                z = __builtin_amdgcn_mfma_f32_16x16x32_bf16(kb[g][1], qf[mi][1], z, 0, 0, 0);
                s[g] = z;
            }
            if (band) {
                int qg = qbw + mi * 16 + r;
                #pragma unroll
                for (int g = 0; g < 2; ++g) {
                    #pragma unroll
                    for (int reg = 0; reg < 4; ++reg) {
                        int kvg = t * 32 + g * 16 + row_g + reg;
                        if (kvg > qg) s[g][reg] = -30000.f;
                    }
                }
            }
            float p0 = __builtin_amdgcn_exp2f(s[0][0]);
            float p1 = __builtin_amdgcn_exp2f(s[0][1]);
            float p2 = __builtin_amdgcn_exp2f(s[0][2]);
            float p3 = __builtin_amdgcn_exp2f(s[0][3]);
            float p4 = __builtin_amdgcn_exp2f(s[1][0]);
            float p5 = __builtin_amdgcn_exp2f(s[1][1]);
            float p6 = __builtin_amdgcn_exp2f(s[1][2]);
            float p7 = __builtin_amdgcn_exp2f(s[1][3]);
            unsigned int w0 = pack_bf16_rh(p0, p1);
            unsigned int w1 = pack_bf16_rh(p2, p3);
            unsigned int w2 = pack_bf16_rh(p4, p5);
            unsigned int w3 = pack_bf16_rh(p6, p7);
            bf16x8 pb;
            { int4 f; f.x = (int)w0; f.y = (int)w1; f.z = (int)w2; f.w = (int)w3;
              __builtin_memcpy(&pb, &f, 16); }

            #pragma unroll
            for (int dg = 0; dg < 4; ++dg)
                oacc[mi][dg] = __builtin_amdgcn_mfma_f32_16x16x32_bf16(vb[dg], pb, oacc[mi][dg], 0, 0, 0);
            oL[mi] = __builtin_amdgcn_mfma_f32_16x16x32_bf16(ones, pb, oL[mi], 0, 0, 0);
        }
    }

    // ---- combine (pure sums over kv, no-max softmax): 3-barrier serial LDS add ----
    __syncthreads();
    if (wave == 0) {
        #pragma unroll
        for (int mi = 0; mi < 4; ++mi) {
            #pragma unroll
            for (int dg = 0; dg < 4; ++dg)
                *reinterpret_cast<f32x4*>(&comb[mi * 16 + r][dg * 16 + row_g]) = oacc[mi][dg];
            if (G == 0) comb[mi * 16 + r][64] = oL[mi][0];
        }
    }
    __syncthreads();
    if (wave == 1) {
        #pragma unroll
        for (int mi = 0; mi < 4; ++mi) {
            #pragma unroll
            for (int dg = 0; dg < 4; ++dg) {
                f32x4 c = *reinterpret_cast<f32x4*>(&comb[mi * 16 + r][dg * 16 + row_g]);
                *reinterpret_cast<f32x4*>(&comb[mi * 16 + r][dg * 16 + row_g]) = c + oacc[mi][dg];
            }
            if (G == 0) comb[mi * 16 + r][64] += oL[mi][0];
        }
    }
    __syncthreads();
    if (wave == 2) {
        #pragma unroll
        for (int mi = 0; mi < 4; ++mi) {
            #pragma unroll
            for (int dg = 0; dg < 4; ++dg) {
                f32x4 c = *reinterpret_cast<f32x4*>(&comb[mi * 16 + r][dg * 16 + row_g]);
                *reinterpret_cast<f32x4*>(&comb[mi * 16 + r][dg * 16 + row_g]) = c + oacc[mi][dg];
            }
            if (G == 0) comb[mi * 16 + r][64] += oL[mi][0];
        }
    }
    __syncthreads();
    if (wave == 3) {
        #pragma unroll
        for (int mi = 0; mi < 4; ++mi) {
            float l = comb[mi * 16 + r][64] + oL[mi][0];
            float il = 1.0f / l;
            size_t tok = (size_t)(b * SEQ + qbw + mi * 16 + r);
            #pragma unroll
            for (int dg = 0; dg < 4; ++dg) {
                f32x4 tot = *reinterpret_cast<f32x4*>(&comb[mi * 16 + r][dg * 16 + row_g]);
                tot = tot + oacc[mi][dg];
                ushort4 o;
                o.x = f2bf(tot[0] * il);
                o.y = f2bf(tot[1] * il);
                o.z = f2bf(tot[2] * il);
                o.w = f2bf(tot[3] * il);
                *reinterpret_cast<ushort4*>(&av[tok * HID + h * DHEAD + dg * 16 + row_g]) = o;
            }
        }
    }
}

extern "C" void kernel_launch(void* const* d_in, const int* in_sizes, int n_in,
                              void* d_out, int out_size, void* d_ws, size_t ws_size,
                              hipStream_t stream) {
    const float* x     = (const float*)d_in[0];
    const float* W_qkv = (const float*)d_in[1];
    const float* b_qkv = (const float*)d_in[2];
    const float* W_o   = (const float*)d_in[3];
    const float* b_o   = (const float*)d_in[4];
    float* out = (float*)d_out;

    const int n_x    = NTOK * HID;
    const int n_wqkv = QKV_N * HID;
    const int n_wo   = HID * HID;
    const int n_qkv  = NTOK * QKV_N;
    const int n_av   = NTOK * HID;

    short* xb    = (short*)d_ws;
    short* wqkvb = xb + n_x;
    short* wob   = wqkvb + n_wqkv;
    short* qkv   = wob + n_wo;
    short* av    = qkv + n_qkv;
    short* vP    = av + n_av;

    // fused cast: x, W_qkv, W_o in ONE launch (R18 verified)
    cast3_f32_bf16<<<(N1 + N2 + N3) / 256, 256, 0, stream>>>(
        x, W_qkv, W_o, (unsigned short*)xb, (unsigned short*)wqkvb, (unsigned short*)wob);

    // qkv = x @ W_qkv^T + b_qkv  -> bf16 [4096][3072]; BN=128 (verified optimum)
    gemm_bt<128, 2><<<(NTOK / 128) * (QKV_N / 128), 256, 0, stream>>>(
        xb, wqkvb, b_qkv, (void*)qkv, NTOK, QKV_N, HID);

    // vP [32 bh][64 T][64 d][32 j] (PV-fragment order)
    transpose_v<<<dim3(SEQ / 64, BATCH * NHEAD), 256, 0, stream>>>(qkv, vP);

    // attention -> av bf16 [4096][1024]; R13 byte-exact (1024 blocks x 4 waves)
    attn_fwd<<<1024, 256, 0, stream>>>(qkv, vP, av);

    // out = av @ W_o^T + b_o  -> fp32
    gemm_bt<64, 0><<<(NTOK / 128) * (HID / 64), 256, 0, stream>>>(
        av, wob, b_o, (void*)out, NTOK, HID, HID);
}

// Round 21
// 111.329 us; speedup vs baseline: 1.2801x; 1.0018x over previous
//
#include <hip/hip_runtime.h>
#include <cstdint>
#include <cstddef>

// ---------- constants for this problem ----------
#define BATCH 2
#define SEQ   2048
#define HID   1024
#define NHEAD 16
#define DHEAD 64
#define QKV_N 3072   // 3*HID
#define NTOK  4096   // BATCH*SEQ

typedef __attribute__((ext_vector_type(4))) float f32x4;
typedef __attribute__((ext_vector_type(8))) short bf16x8;

#define QSCL 0.18033688011112042f   // (1/8) * log2(e), folded into Q at GEMM epilogue

__device__ inline unsigned short f2bf(float f) {
    union { float f; unsigned int u; } v; v.f = f;
    unsigned int u = v.u;
    unsigned int r = (u + 0x7fffu + ((u >> 16) & 1u)) >> 16;
    return (unsigned short)r;
}

// pack two positive floats to bf16 pair (round-half-up): P in [0,1], no NaN/inf.
__device__ __forceinline__ unsigned int pack_bf16_rh(float a, float b) {
    union { float f; unsigned int u; } ua, ub;
    ua.f = a; ub.f = b;
    return ((ua.u + 0x8000u) >> 16) | ((ub.u + 0x8000u) & 0xffff0000u);
}

__device__ __forceinline__ void gload_lds16(const void* g, void* l) {
    __builtin_amdgcn_global_load_lds(
        (const __attribute__((address_space(1))) void*)g,
        (__attribute__((address_space(3))) void*)l, 16, 0, 0);
}

// ---------- fused cast fp32 -> bf16 for x, W_qkv, W_o (one launch; R18 verified) ----------
#define N1 (NTOK * HID / 4)     // x:     1,048,576 float4
#define N2 (QKV_N * HID / 4)    // W_qkv:   786,432
#define N3 (HID * HID / 4)      // W_o:     262,144

__global__ __launch_bounds__(256) void cast3_f32_bf16(const float* __restrict__ x,
                                                      const float* __restrict__ wqkv,
                                                      const float* __restrict__ wo,
                                                      unsigned short* __restrict__ xb,
                                                      unsigned short* __restrict__ wqkvb,
                                                      unsigned short* __restrict__ wob) {
    int i = blockIdx.x * blockDim.x + threadIdx.x;
    const float* src;
    unsigned short* dst;
    int k;
    if (i < N1)            { src = x;    dst = xb;    k = i; }
    else if (i < N1 + N2)  { src = wqkv; dst = wqkvb; k = i - N1; }
    else                   { src = wo;   dst = wob;   k = i - N1 - N2; }
    float4 v = reinterpret_cast<const float4*>(src)[k];
    ushort4 o;
    o.x = f2bf(v.x); o.y = f2bf(v.y); o.z = f2bf(v.z); o.w = f2bf(v.w);
    reinterpret_cast<ushort4*>(dst)[k] = o;
}

// ---------- GEMM, 2-phase dbuf pipeline, BK=32, BN=128/64 (R5/R13 verified) ----------
template<int BN, int OUT_MODE>
__global__ __launch_bounds__(256) void gemm_bt(const short* __restrict__ A,
                                               const short* __restrict__ B,
                                               const float* __restrict__ bias,
                                               void* __restrict__ Cout,
                                               int M, int N, int K) {
    constexpr int WTN = BN / 2;
    constexpr int NJ  = WTN / 16;
    constexpr int NBC = BN / 64;

    __shared__ short sA[2][128 * 32];
    __shared__ short sB[2][BN * 32];

    const int tid  = threadIdx.x;
    const int lane = tid & 63;
    const int wave = tid >> 6;
    const int wm = wave >> 1, wn = wave & 1;

    const int nwg = gridDim.x;
    const int swz = (blockIdx.x & 7) * (nwg >> 3) + (blockIdx.x >> 3);
    const int tiles_n = N / BN;
    const int m0 = (swz / tiles_n) * 128;
    const int n0 = (swz % tiles_n) * BN;

    f32x4 acc[4][NJ];
    #pragma unroll
    for (int i = 0; i < 4; ++i)
        #pragma unroll
        for (int j = 0; j < NJ; ++j) acc[i][j] = (f32x4){0.f, 0.f, 0.f, 0.f};

    const int r = lane & 15;
    const int G = lane >> 4;

    #define GSTAGE(kt_, buf_)                                                          \
        {                                                                              \
            _Pragma("unroll")                                                          \
            for (int i = 0; i < 2; ++i) {                                              \
                int ga = (i * 4 + wave) * 64 + lane;                                   \
                int row = ga >> 2, gcol = (ga & 3) ^ (row & 3);                        \
                gload_lds16(A + (size_t)(m0 + row) * K + (kt_) + gcol * 8,             \
                            &sA[buf_][(i * 4 + wave) * 512]);                          \
            }                                                                          \
            _Pragma("unroll")                                                          \
            for (int i = 0; i < NBC; ++i) {                                            \
                int gb = (i * 4 + wave) * 64 + lane;                                   \
                int row = gb >> 2, gcol = (gb & 3) ^ (row & 3);                        \
                gload_lds16(B + (size_t)(n0 + row) * K + (kt_) + gcol * 8,             \
                            &sB[buf_][(i * 4 + wave) * 512]);                          \
            }                                                                          \
        }

    GSTAGE(0, 0);
    __syncthreads();
    int cur = 0;

    const int nsteps = K >> 5;
    for (int ks = 0; ks < nsteps; ++ks) {
        if (ks + 1 < nsteps) GSTAGE((ks + 1) * 32, cur ^ 1);

        const int sg = G ^ (r & 3);
        bf16x8 af[4], bfr[NJ];
        #pragma unroll
        for (int i = 0; i < 4; ++i) {
            int row = wm * 64 + i * 16 + r;
            af[i] = *reinterpret_cast<const bf16x8*>(&sA[cur][row * 32 + sg * 8]);
        }
        #pragma unroll
        for (int j = 0; j < NJ; ++j) {
            int row = wn * WTN + j * 16 + r;
            bfr[j] = *reinterpret_cast<const bf16x8*>(&sB[cur][row * 32 + sg * 8]);
        }
        #pragma unroll
        for (int i = 0; i < 4; ++i)
            #pragma unroll
            for (int j = 0; j < NJ; ++j)
                acc[i][j] = __builtin_amdgcn_mfma_f32_16x16x32_bf16(af[i], bfr[j], acc[i][j], 0, 0, 0);

        __syncthreads();
        cur ^= 1;
    }
    #undef GSTAGE

    const int col_l = lane & 15;
    const int row_g = (lane >> 4) * 4;
    #pragma unroll
    for (int i = 0; i < 4; ++i) {
        #pragma unroll
        for (int j = 0; j < NJ; ++j) {
            int nn = n0 + wn * WTN + j * 16 + col_l;
            float bv = bias[nn];
            float scl = (OUT_MODE == 2 && nn < HID) ? QSCL : 1.0f;
            #pragma unroll
            for (int reg = 0; reg < 4; ++reg) {
                int mm = m0 + wm * 64 + i * 16 + row_g + reg;
                float v = (acc[i][j][reg] + bv) * scl;
                if (OUT_MODE == 0) {
                    reinterpret_cast<float*>(Cout)[(size_t)mm * N + nn] = v;
                } else {
                    reinterpret_cast<unsigned short*>(Cout)[(size_t)mm * N + nn] = f2bf(v);
                }
            }
        }
    }
}

// ---------- transpose V part of qkv -> vP [bh][T][d][j] (PV-fragment order) ----------
// (unchanged from R11 -- verified)
#define TLDP 72
__global__ __launch_bounds__(256) void transpose_v(const short* __restrict__ qkv,
                                                   short* __restrict__ vP) {
    const int st = blockIdx.x;
    const int bh = blockIdx.y;
    const int b  = bh >> 4, h = bh & 15;
    __shared__ short ld[64 * TLDP];
    const int tid = threadIdx.x;

    #pragma unroll
    for (int i = 0; i < 2; ++i) {
        int idx = i * 256 + tid;
        int row = idx >> 3, c = idx & 7;
        int4 v = *reinterpret_cast<const int4*>(
            qkv + ((size_t)(b * SEQ + st * 64 + row)) * QKV_N + 2 * HID + h * DHEAD + c * 8);
        *reinterpret_cast<int4*>(&ld[row * TLDP + c * 8]) = v;
    }
    __syncthreads();
    #pragma unroll
    for (int i = 0; i < 2; ++i) {
        int u  = i * 256 + tid;
        int Tp = u >> 8;
        int d  = (u >> 2) & 63;
        int p  = u & 3;
        int b0 = Tp * 32 + 4 * p;
        int b1 = b0 + 16;
        ushort4 o0, o1;
        o0.x = (unsigned short)ld[(b0 + 0) * TLDP + d];
        o0.y = (unsigned short)ld[(b0 + 1) * TLDP + d];
        o0.z = (unsigned short)ld[(b0 + 2) * TLDP + d];
        o0.w = (unsigned short)ld[(b0 + 3) * TLDP + d];
        o1.x = (unsigned short)ld[(b1 + 0) * TLDP + d];
        o1.y = (unsigned short)ld[(b1 + 1) * TLDP + d];
        o1.z = (unsigned short)ld[(b1 + 2) * TLDP + d];
        o1.w = (unsigned short)ld[(b1 + 3) * TLDP + d];
        size_t out = ((size_t)((bh * 64 + st * 2 + Tp) * 64 + d)) * 32 + p * 8;
        *reinterpret_cast<ushort4*>(&vP[out])     = o0;
        *reinterpret_cast<ushort4*>(&vP[out + 4]) = o1;
    }
}

// ---------- flash attention (causal): R20 body + unroll-2 t-loop (compiler pipelining) ----------
__global__ __launch_bounds__(256) void attn_fwd(const short* __restrict__ qkv,
                                                const short* __restrict__ vP,
                                                short* __restrict__ av) {
    const int bid = blockIdx.x;
    const int qb  = 31 - (bid >> 5);     // 0..31, heaviest blocks dispatched first
    const int bh  = bid & 31;            // bid%8 == bh%8 -> per-head XCD affinity
    const int b   = bh >> 4;
    const int h   = bh & 15;

    __shared__ float comb[64][68];       // cols 0..63 = O[q][d], col 64 = L[q]

    const int tid  = threadIdx.x;
    const int lane = tid & 63;
    const int wave = tid >> 6;           // 0..3 (kv-split)
    const int r    = lane & 15;
    const int G    = lane >> 4;
    const int row_g = G * 4;

    const int qbw = qb * 64;             // first q row of this block

    // Q fragments for 4 mi (pre-scaled by QSCL); B-frag: col = q = r, k = d
    bf16x8 qf[4][2];
    #pragma unroll
    for (int mi = 0; mi < 4; ++mi) {
        const short* Qg = qkv + ((size_t)(b * SEQ + qbw + mi * 16 + r)) * QKV_N + h * DHEAD;
        qf[mi][0] = *reinterpret_cast<const bf16x8*>(Qg + G * 8);
        qf[mi][1] = *reinterpret_cast<const bf16x8*>(Qg + 32 + G * 8);
    }

    f32x4 oacc[4][4];
    f32x4 oL[4];
    #pragma unroll
    for (int mi = 0; mi < 4; ++mi) {
        oL[mi] = (f32x4){0.f, 0.f, 0.f, 0.f};
        #pragma unroll
        for (int dg = 0; dg < 4; ++dg) oacc[mi][dg] = (f32x4){0.f, 0.f, 0.f, 0.f};
    }

    bf16x8 ones;
    #pragma unroll
    for (int e = 0; e < 8; ++e) ones[e] = (short)0x3f80;   // bf16 1.0

    // per-lane base pointers (strength-reduced: incremented each iteration)
    const short* kpt = qkv + (size_t)(b * SEQ + wave * 32) * QKV_N + HID + h * DHEAD
                       + r * QKV_N + G * 8;
    const short* vpt = vP + (size_t)(bh * 64 + wave) * 2048 + r * 32 + G * 8;
    const ptrdiff_t KSTEP = (ptrdiff_t)128 * QKV_N;
    const ptrdiff_t VSTEP = 4 * 2048;
    const int KG1 = 16 * QKV_N;

    const int tlast = 2 * qb + 1;
    // unroll 2: gives the scheduler a straight-line region holding TWO iterations'
    // independent loads + compute, so it can hoist iter i+1's 12 L2 loads above
    // iter i's exp/pack/MFMA on its own (manual cross-iteration pipelining was
    // sunk by the compiler in R16/R17; plain unroll is the sanctioned path).
    #pragma unroll 2
    for (int t = wave; t <= tlast; t += 4) {
        int4 k00 = *reinterpret_cast<const int4*>(kpt);
        int4 k01 = *reinterpret_cast<const int4*>(kpt + 32);
        int4 k10 = *reinterpret_cast<const int4*>(kpt + KG1);
        int4 k11 = *reinterpret_cast<const int4*>(kpt + KG1 + 32);
        int4 v0 = *reinterpret_cast<const int4*>(vpt);
        int4 v1 = *reinterpret_cast<const int4*>(vpt + 16 * 32);
        int4 v2 = *reinterpret_cast<const int4*>(vpt + 32 * 32);
        int4 v3 = *reinterpret_cast<const int4*>(vpt + 48 * 32);
        kpt += KSTEP;
        vpt += VSTEP;

        bf16x8 kb[2][2], vb[4];
        __builtin_memcpy(&kb[0][0], &k00, 16);
        __builtin_memcpy(&kb[0][1], &k01, 16);
        __builtin_memcpy(&kb[1][0], &k10, 16);
        __builtin_memcpy(&kb[1][1], &k11, 16);
        __builtin_memcpy(&vb[0], &v0, 16);
        __builtin_memcpy(&vb[1], &v1, 16);
        __builtin_memcpy(&vb[2], &v2, 16);
        __builtin_memcpy(&vb[3], &v3, 16);

        const bool band = (t >= 2 * qb);

        #pragma unroll
        for (int mi = 0; mi < 4; ++mi) {
            f32x4 s[2];
            #pragma unroll
            for (int g = 0; g < 2; ++g) {
                f32x4 z = (f32x4){0.f, 0.f, 0.f, 0.f};
                z = __builtin_amdgcn_mfma_f32_16x16x32_bf16(kb[g][0], qf[mi][0], z, 0, 0, 0);
                z = __builtin_amdgcn_mfma_f32_16x16x32_bf16(kb[g][1], qf[mi][1], z, 0, 0, 0);
                s[g] = z;
            }
            if (band) {
                int qg = qbw + mi * 16 + r;
                #pragma unroll
                for (int g = 0; g < 2; ++g) {
                    #pragma unroll
                    for (int reg = 0; reg < 4; ++reg) {
                        int kvg = t * 32 + g * 16 + row_g + reg;
                        if (kvg > qg) s[g][reg] = -30000.f;
                    }
                }
            }
            float p0 = __builtin_amdgcn_exp2f(s[0][0]);
            float p1 = __builtin_amdgcn_exp2f(s[0][1]);
            float p2 = __builtin_amdgcn_exp2f(s[0][2]);
            float p3 = __builtin_amdgcn_exp2f(s[0][3]);
            float p4 = __builtin_amdgcn_exp2f(s[1][0]);
            float p5 = __builtin_amdgcn_exp2f(s[1][1]);
            float p6 = __builtin_amdgcn_exp2f(s[1][2]);
            float p7 = __builtin_amdgcn_exp2f(s[1][3]);
            unsigned int w0 = pack_bf16_rh(p0, p1);
            unsigned int w1 = pack_bf16_rh(p2, p3);
            unsigned int w2 = pack_bf16_rh(p4, p5);
            unsigned int w3 = pack_bf16_rh(p6, p7);
            bf16x8 pb;
            { int4 f; f.x = (int)w0; f.y = (int)w1; f.z = (int)w2; f.w = (int)w3;
              __builtin_memcpy(&pb, &f, 16); }

            #pragma unroll
            for (int dg = 0; dg < 4; ++dg)
                oacc[mi][dg] = __builtin_amdgcn_mfma_f32_16x16x32_bf16(vb[dg], pb, oacc[mi][dg], 0, 0, 0);
            oL[mi] = __builtin_amdgcn_mfma_f32_16x16x32_bf16(ones, pb, oL[mi], 0, 0, 0);
        }
    }

    // ---- combine (pure sums over kv, no-max softmax): 3-barrier serial LDS add ----
    __syncthreads();
    if (wave == 0) {
        #pragma unroll
        for (int mi = 0; mi < 4; ++mi) {
            #pragma unroll
            for (int dg = 0; dg < 4; ++dg)
                *reinterpret_cast<f32x4*>(&comb[mi * 16 + r][dg * 16 + row_g]) = oacc[mi][dg];
            if (G == 0) comb[mi * 16 + r][64] = oL[mi][0];
        }
    }
    __syncthreads();
    if (wave == 1) {
        #pragma unroll
        for (int mi = 0; mi < 4; ++mi) {
            #pragma unroll
            for (int dg = 0; dg < 4; ++dg) {
                f32x4 c = *reinterpret_cast<f32x4*>(&comb[mi * 16 + r][dg * 16 + row_g]);
                *reinterpret_cast<f32x4*>(&comb[mi * 16 + r][dg * 16 + row_g]) = c + oacc[mi][dg];
            }
            if (G == 0) comb[mi * 16 + r][64] += oL[mi][0];
        }
    }
    __syncthreads();
    if (wave == 2) {
        #pragma unroll
        for (int mi = 0; mi < 4; ++mi) {
            #pragma unroll
            for (int dg = 0; dg < 4; ++dg) {
                f32x4 c = *reinterpret_cast<f32x4*>(&comb[mi * 16 + r][dg * 16 + row_g]);
                *reinterpret_cast<f32x4*>(&comb[mi * 16 + r][dg * 16 + row_g]) = c + oacc[mi][dg];
            }
            if (G == 0) comb[mi * 16 + r][64] += oL[mi][0];
        }
    }
    __syncthreads();
    if (wave == 3) {
        #pragma unroll
        for (int mi = 0; mi < 4; ++mi) {
            float l = comb[mi * 16 + r][64] + oL[mi][0];
            float il = 1.0f / l;
            size_t tok = (size_t)(b * SEQ + qbw + mi * 16 + r);
            #pragma unroll
            for (int dg = 0; dg < 4; ++dg) {
                f32x4 tot = *reinterpret_cast<f32x4*>(&comb[mi * 16 + r][dg * 16 + row_g]);
                tot = tot + oacc[mi][dg];
                ushort4 o;
                o.x = f2bf(tot[0] * il);
                o.y = f2bf(tot[1] * il);
                o.z = f2bf(tot[2] * il);
                o.w = f2bf(tot[3] * il);
                *reinterpret_cast<ushort4*>(&av[tok * HID + h * DHEAD + dg * 16 + row_g]) = o;
            }
        }
    }
}

extern "C" void kernel_launch(void* const* d_in, const int* in_sizes, int n_in,
                              void* d_out, int out_size, void* d_ws, size_t ws_size,
                              hipStream_t stream) {
    const float* x     = (const float*)d_in[0];
    const float* W_qkv = (const float*)d_in[1];
    const float* b_qkv = (const float*)d_in[2];
    const float* W_o   = (const float*)d_in[3];
    const float* b_o   = (const float*)d_in[4];
    float* out = (float*)d_out;

    const int n_x    = NTOK * HID;
    const int n_wqkv = QKV_N * HID;
    const int n_wo   = HID * HID;
    const int n_qkv  = NTOK * QKV_N;
    const int n_av   = NTOK * HID;

    short* xb    = (short*)d_ws;
    short* wqkvb = xb + n_x;
    short* wob   = wqkvb + n_wqkv;
    short* qkv   = wob + n_wo;
    short* av    = qkv + n_qkv;
    short* vP    = av + n_av;

    // fused cast: x, W_qkv, W_o in ONE launch (R18 verified)
    cast3_f32_bf16<<<(N1 + N2 + N3) / 256, 256, 0, stream>>>(
        x, W_qkv, W_o, (unsigned short*)xb, (unsigned short*)wqkvb, (unsigned short*)wob);

    // qkv = x @ W_qkv^T + b_qkv  -> bf16 [4096][3072]; BN=128 (verified optimum)
    gemm_bt<128, 2><<<(NTOK / 128) * (QKV_N / 128), 256, 0, stream>>>(
        xb, wqkvb, b_qkv, (void*)qkv, NTOK, QKV_N, HID);

    // vP [32 bh][64 T][64 d][32 j] (PV-fragment order)
    transpose_v<<<dim3(SEQ / 64, BATCH * NHEAD), 256, 0, stream>>>(qkv, vP);

    // attention -> av bf16 [4096][1024]; R13 body + unroll-2 pipeline
    attn_fwd<<<1024, 256, 0, stream>>>(qkv, vP, av);

    // out = av @ W_o^T + b_o  -> fp32
    gemm_bt<64, 0><<<(NTOK / 128) * (HID / 64), 256, 0, stream>>>(
        av, wob, b_o, (void*)out, NTOK, HID, HID);
}

// Round 24
// 111.206 us; speedup vs baseline: 1.2815x; 1.0011x over previous
//
#include <hip/hip_runtime.h>
#include <cstdint>
#include <cstddef>

// ---------- constants for this problem ----------
#define BATCH 2
#define SEQ   2048
#define HID   1024
#define NHEAD 16
#define DHEAD 64
#define QKV_N 3072   // 3*HID
#define NTOK  4096   // BATCH*SEQ

typedef __attribute__((ext_vector_type(4))) float f32x4;
typedef __attribute__((ext_vector_type(8))) short bf16x8;

#define QSCL 0.18033688011112042f   // (1/8) * log2(e), folded into Q at GEMM epilogue

__device__ inline unsigned short f2bf(float f) {
    union { float f; unsigned int u; } v; v.f = f;
    unsigned int u = v.u;
    unsigned int r = (u + 0x7fffu + ((u >> 16) & 1u)) >> 16;
    return (unsigned short)r;
}

// pack two positive floats to bf16 pair (round-half-up): P in [0,1], no NaN/inf.
__device__ __forceinline__ unsigned int pack_bf16_rh(float a, float b) {
    union { float f; unsigned int u; } ua, ub;
    ua.f = a; ub.f = b;
    return ((ua.u + 0x8000u) >> 16) | ((ub.u + 0x8000u) & 0xffff0000u);
}

__device__ __forceinline__ void gload_lds16(const void* g, void* l) {
    __builtin_amdgcn_global_load_lds(
        (const __attribute__((address_space(1))) void*)g,
        (__attribute__((address_space(3))) void*)l, 16, 0, 0);
}

// ---------- fused cast fp32 -> bf16 for x, W_qkv, W_o (one launch; R18 verified) ----------
#define N1 (NTOK * HID / 4)     // x:     1,048,576 float4
#define N2 (QKV_N * HID / 4)    // W_qkv:   786,432
#define N3 (HID * HID / 4)      // W_o:     262,144

__global__ __launch_bounds__(256) void cast3_f32_bf16(const float* __restrict__ x,
                                                      const float* __restrict__ wqkv,
                                                      const float* __restrict__ wo,
                                                      unsigned short* __restrict__ xb,
                                                      unsigned short* __restrict__ wqkvb,
                                                      unsigned short* __restrict__ wob) {
    int i = blockIdx.x * blockDim.x + threadIdx.x;
    const float* src;
    unsigned short* dst;
    int k;
    if (i < N1)            { src = x;    dst = xb;    k = i; }
    else if (i < N1 + N2)  { src = wqkv; dst = wqkvb; k = i - N1; }
    else                   { src = wo;   dst = wob;   k = i - N1 - N2; }
    float4 v = reinterpret_cast<const float4*>(src)[k];
    ushort4 o;
    o.x = f2bf(v.x); o.y = f2bf(v.y); o.z = f2bf(v.z); o.w = f2bf(v.w);
    reinterpret_cast<ushort4*>(dst)[k] = o;
}

// ---------- GEMM, 2-phase dbuf pipeline, BK=32, BN=128/64 (R5/R13 verified) ----------
template<int BN, int OUT_MODE>
__global__ __launch_bounds__(256) void gemm_bt(const short* __restrict__ A,
                                               const short* __restrict__ B,
                                               const float* __restrict__ bias,
                                               void* __restrict__ Cout,
                                               int M, int N, int K) {
    constexpr int WTN = BN / 2;
    constexpr int NJ  = WTN / 16;
    constexpr int NBC = BN / 64;

    __shared__ short sA[2][128 * 32];
    __shared__ short sB[2][BN * 32];

    const int tid  = threadIdx.x;
    const int lane = tid & 63;
    const int wave = tid >> 6;
    const int wm = wave >> 1, wn = wave & 1;

    const int nwg = gridDim.x;
    const int swz = (blockIdx.x & 7) * (nwg >> 3) + (blockIdx.x >> 3);
    const int tiles_n = N / BN;
    const int m0 = (swz / tiles_n) * 128;
    const int n0 = (swz % tiles_n) * BN;

    f32x4 acc[4][NJ];
    #pragma unroll
    for (int i = 0; i < 4; ++i)
        #pragma unroll
        for (int j = 0; j < NJ; ++j) acc[i][j] = (f32x4){0.f, 0.f, 0.f, 0.f};

    const int r = lane & 15;
    const int G = lane >> 4;

    #define GSTAGE(kt_, buf_)                                                          \
        {                                                                              \
            _Pragma("unroll")                                                          \
            for (int i = 0; i < 2; ++i) {                                              \
                int ga = (i * 4 + wave) * 64 + lane;                                   \
                int row = ga >> 2, gcol = (ga & 3) ^ (row & 3);                        \
                gload_lds16(A + (size_t)(m0 + row) * K + (kt_) + gcol * 8,             \
                            &sA[buf_][(i * 4 + wave) * 512]);                          \
            }                                                                          \
            _Pragma("unroll")                                                          \
            for (int i = 0; i < NBC; ++i) {                                            \
                int gb = (i * 4 + wave) * 64 + lane;                                   \
                int row = gb >> 2, gcol = (gb & 3) ^ (row & 3);                        \
                gload_lds16(B + (size_t)(n0 + row) * K + (kt_) + gcol * 8,             \
                            &sB[buf_][(i * 4 + wave) * 512]);                          \
            }                                                                          \
        }

    GSTAGE(0, 0);
    __syncthreads();
    int cur = 0;

    const int nsteps = K >> 5;
    for (int ks = 0; ks < nsteps; ++ks) {
        if (ks + 1 < nsteps) GSTAGE((ks + 1) * 32, cur ^ 1);

        const int sg = G ^ (r & 3);
        bf16x8 af[4], bfr[NJ];
        #pragma unroll
        for (int i = 0; i < 4; ++i) {
            int row = wm * 64 + i * 16 + r;
            af[i] = *reinterpret_cast<const bf16x8*>(&sA[cur][row * 32 + sg * 8]);
        }
        #pragma unroll
        for (int j = 0; j < NJ; ++j) {
            int row = wn * WTN + j * 16 + r;
            bfr[j] = *reinterpret_cast<const bf16x8*>(&sB[cur][row * 32 + sg * 8]);
        }
        #pragma unroll
        for (int i = 0; i < 4; ++i)
            #pragma unroll
            for (int j = 0; j < NJ; ++j)
                acc[i][j] = __builtin_amdgcn_mfma_f32_16x16x32_bf16(af[i], bfr[j], acc[i][j], 0, 0, 0);

        __syncthreads();
        cur ^= 1;
    }
    #undef GSTAGE

    const int col_l = lane & 15;
    const int row_g = (lane >> 4) * 4;
    #pragma unroll
    for (int i = 0; i < 4; ++i) {
        #pragma unroll
        for (int j = 0; j < NJ; ++j) {
            int nn = n0 + wn * WTN + j * 16 + col_l;
            float bv = bias[nn];
            float scl = (OUT_MODE == 2 && nn < HID) ? QSCL : 1.0f;
            #pragma unroll
            for (int reg = 0; reg < 4; ++reg) {
                int mm = m0 + wm * 64 + i * 16 + row_g + reg;
                float v = (acc[i][j][reg] + bv) * scl;
                if (OUT_MODE == 0) {
                    reinterpret_cast<float*>(Cout)[(size_t)mm * N + nn] = v;
                } else {
                    reinterpret_cast<unsigned short*>(Cout)[(size_t)mm * N + nn] = f2bf(v);
                }
            }
        }
    }
}

// ---------- transpose V part of qkv -> vP [bh][T][d][j] (PV-fragment order) ----------
#define TLDP 72
__global__ __launch_bounds__(256) void transpose_v(const short* __restrict__ qkv,
                                                   short* __restrict__ vP) {
    const int st = blockIdx.x;
    const int bh = blockIdx.y;
    const int b  = bh >> 4, h = bh & 15;
    __shared__ short ld[64 * TLDP];
    const int tid = threadIdx.x;

    #pragma unroll
    for (int i = 0; i < 2; ++i) {
        int idx = i * 256 + tid;
        int row = idx >> 3, c = idx & 7;
        int4 v = *reinterpret_cast<const int4*>(
            qkv + ((size_t)(b * SEQ + st * 64 + row)) * QKV_N + 2 * HID + h * DHEAD + c * 8);
        *reinterpret_cast<int4*>(&ld[row * TLDP + c * 8]) = v;
    }
    __syncthreads();
    #pragma unroll
    for (int i = 0; i < 2; ++i) {
        int u  = i * 256 + tid;
        int Tp = u >> 8;
        int d  = (u >> 2) & 63;
        int p  = u & 3;
        int b0 = Tp * 32 + 4 * p;
        int b1 = b0 + 16;
        ushort4 o0, o1;
        o0.x = (unsigned short)ld[(b0 + 0) * TLDP + d];
        o0.y = (unsigned short)ld[(b0 + 1) * TLDP + d];
        o0.z = (unsigned short)ld[(b0 + 2) * TLDP + d];
        o0.w = (unsigned short)ld[(b0 + 3) * TLDP + d];
        o1.x = (unsigned short)ld[(b1 + 0) * TLDP + d];
        o1.y = (unsigned short)ld[(b1 + 1) * TLDP + d];
        o1.z = (unsigned short)ld[(b1 + 2) * TLDP + d];
        o1.w = (unsigned short)ld[(b1 + 3) * TLDP + d];
        size_t out = ((size_t)((bh * 64 + st * 2 + Tp) * 64 + d)) * 32 + p * 8;
        *reinterpret_cast<ushort4*>(&vP[out])     = o0;
        *reinterpret_cast<ushort4*>(&vP[out + 4]) = o1;
    }
}

// ---------- flash attention (causal): R13 byte-exact (best verified, 48.2 us) ----------
__global__ __launch_bounds__(256) void attn_fwd(const short* __restrict__ qkv,
                                                const short* __restrict__ vP,
                                                short* __restrict__ av) {
    const int bid = blockIdx.x;
    const int qb  = 31 - (bid >> 5);     // 0..31, heaviest blocks dispatched first
    const int bh  = bid & 31;            // bid%8 == bh%8 -> per-head XCD affinity
    const int b   = bh >> 4;
    const int h   = bh & 15;

    __shared__ float comb[64][68];       // cols 0..63 = O[q][d], col 64 = L[q]

    const int tid  = threadIdx.x;
    const int lane = tid & 63;
    const int wave = tid >> 6;           // 0..3 (kv-split)
    const int r    = lane & 15;
    const int G    = lane >> 4;
    const int row_g = G * 4;

    const int qbw = qb * 64;             // first q row of this block

    // Q fragments for 4 mi (pre-scaled by QSCL); B-frag: col = q = r, k = d
    bf16x8 qf[4][2];
    #pragma unroll
    for (int mi = 0; mi < 4; ++mi) {
        const short* Qg = qkv + ((size_t)(b * SEQ + qbw + mi * 16 + r)) * QKV_N + h * DHEAD;
        qf[mi][0] = *reinterpret_cast<const bf16x8*>(Qg + G * 8);
        qf[mi][1] = *reinterpret_cast<const bf16x8*>(Qg + 32 + G * 8);
    }

    f32x4 oacc[4][4];
    f32x4 oL[4];
    #pragma unroll
    for (int mi = 0; mi < 4; ++mi) {
        oL[mi] = (f32x4){0.f, 0.f, 0.f, 0.f};
        #pragma unroll
        for (int dg = 0; dg < 4; ++dg) oacc[mi][dg] = (f32x4){0.f, 0.f, 0.f, 0.f};
    }

    bf16x8 ones;
    #pragma unroll
    for (int e = 0; e < 8; ++e) ones[e] = (short)0x3f80;   // bf16 1.0

    // per-lane base pointers (strength-reduced: incremented each iteration)
    const short* kpt = qkv + (size_t)(b * SEQ + wave * 32) * QKV_N + HID + h * DHEAD
                       + r * QKV_N + G * 8;
    const short* vpt = vP + (size_t)(bh * 64 + wave) * 2048 + r * 32 + G * 8;
    const ptrdiff_t KSTEP = (ptrdiff_t)128 * QKV_N;
    const ptrdiff_t VSTEP = 4 * 2048;
    const int KG1 = 16 * QKV_N;

    const int tlast = 2 * qb + 1;
    for (int t = wave; t <= tlast; t += 4) {
        int4 k00 = *reinterpret_cast<const int4*>(kpt);
        int4 k01 = *reinterpret_cast<const int4*>(kpt + 32);
        int4 k10 = *reinterpret_cast<const int4*>(kpt + KG1);
        int4 k11 = *reinterpret_cast<const int4*>(kpt + KG1 + 32);
        int4 v0 = *reinterpret_cast<const int4*>(vpt);
        int4 v1 = *reinterpret_cast<const int4*>(vpt + 16 * 32);
        int4 v2 = *reinterpret_cast<const int4*>(vpt + 32 * 32);
        int4 v3 = *reinterpret_cast<const int4*>(vpt + 48 * 32);
        kpt += KSTEP;
        vpt += VSTEP;

        bf16x8 kb[2][2], vb[4];
        __builtin_memcpy(&kb[0][0], &k00, 16);
        __builtin_memcpy(&kb[0][1], &k01, 16);
        __builtin_memcpy(&kb[1][0], &k10, 16);
        __builtin_memcpy(&kb[1][1], &k11, 16);
        __builtin_memcpy(&vb[0], &v0, 16);
        __builtin_memcpy(&vb[1], &v1, 16);
        __builtin_memcpy(&vb[2], &v2, 16);
        __builtin_memcpy(&vb[3], &v3, 16);

        const bool band = (t >= 2 * qb);

        #pragma unroll
        for (int mi = 0; mi < 4; ++mi) {
            f32x4 s[2];
            #pragma unroll
            for (int g = 0; g < 2; ++g) {
                f32x4 z = (f32x4){0.f, 0.f, 0.f, 0.f};
                z = __builtin_amdgcn_mfma_f32_16x16x32_bf16(kb[g][0], qf[mi][0], z, 0, 0, 0);
                z = __builtin_amdgcn_mfma_f32_16x16x32_bf16(kb[g][1], qf[mi][1], z, 0, 0, 0);
                s[g] = z;
            }
            if (band) {
                int qg = qbw + mi * 16 + r;
                #pragma unroll
                for (int g = 0; g < 2; ++g) {
                    #pragma unroll
                    for (int reg = 0; reg < 4; ++reg) {
                        int kvg = t * 32 + g * 16 + row_g + reg;
                        if (kvg > qg) s[g][reg] = -30000.f;
                    }
                }
            }
            float p0 = __builtin_amdgcn_exp2f(s[0][0]);
            float p1 = __builtin_amdgcn_exp2f(s[0][1]);
            float p2 = __builtin_amdgcn_exp2f(s[0][2]);
            float p3 = __builtin_amdgcn_exp2f(s[0][3]);
            float p4 = __builtin_amdgcn_exp2f(s[1][0]);
            float p5 = __builtin_amdgcn_exp2f(s[1][1]);
            float p6 = __builtin_amdgcn_exp2f(s[1][2]);
            float p7 = __builtin_amdgcn_exp2f(s[1][3]);
            unsigned int w0 = pack_bf16_rh(p0, p1);
            unsigned int w1 = pack_bf16_rh(p2, p3);
            unsigned int w2 = pack_bf16_rh(p4, p5);
            unsigned int w3 = pack_bf16_rh(p6, p7);
            bf16x8 pb;
            { int4 f; f.x = (int)w0; f.y = (int)w1; f.z = (int)w2; f.w = (int)w3;
              __builtin_memcpy(&pb, &f, 16); }

            #pragma unroll
            for (int dg = 0; dg < 4; ++dg)
                oacc[mi][dg] = __builtin_amdgcn_mfma_f32_16x16x32_bf16(vb[dg], pb, oacc[mi][dg], 0, 0, 0);
            oL[mi] = __builtin_amdgcn_mfma_f32_16x16x32_bf16(ones, pb, oL[mi], 0, 0, 0);
        }
    }

    // ---- combine (pure sums over kv, no-max softmax): 3-barrier serial LDS add ----
    __syncthreads();
    if (wave == 0) {
        #pragma unroll
        for (int mi = 0; mi < 4; ++mi) {
            #pragma unroll
            for (int dg = 0; dg < 4; ++dg)
                *reinterpret_cast<f32x4*>(&comb[mi * 16 + r][dg * 16 + row_g]) = oacc[mi][dg];
            if (G == 0) comb[mi * 16 + r][64] = oL[mi][0];
        }
    }
    __syncthreads();
    if (wave == 1) {
        #pragma unroll
        for (int mi = 0; mi < 4; ++mi) {
            #pragma unroll
            for (int dg = 0; dg < 4; ++dg) {
                f32x4 c = *reinterpret_cast<f32x4*>(&comb[mi * 16 + r][dg * 16 + row_g]);
                *reinterpret_cast<f32x4*>(&comb[mi * 16 + r][dg * 16 + row_g]) = c + oacc[mi][dg];
            }
            if (G == 0) comb[mi * 16 + r][64] += oL[mi][0];
        }
    }
    __syncthreads();
    if (wave == 2) {
        #pragma unroll
        for (int mi = 0; mi < 4; ++mi) {
            #pragma unroll
            for (int dg = 0; dg < 4; ++dg) {
                f32x4 c = *reinterpret_cast<f32x4*>(&comb[mi * 16 + r][dg * 16 + row_g]);
                *reinterpret_cast<f32x4*>(&comb[mi * 16 + r][dg * 16 + row_g]) = c + oacc[mi][dg];
            }
            if (G == 0) comb[mi * 16 + r][64] += oL[mi][0];
        }
    }
    __syncthreads();
    if (wave == 3) {
        #pragma unroll
        for (int mi = 0; mi < 4; ++mi) {
            float l = comb[mi * 16 + r][64] + oL[mi][0];
            float il = 1.0f / l;
            size_t tok = (size_t)(b * SEQ + qbw + mi * 16 + r);
            #pragma unroll
            for (int dg = 0; dg < 4; ++dg) {
                f32x4 tot = *reinterpret_cast<f32x4*>(&comb[mi * 16 + r][dg * 16 + row_g]);
                tot = tot + oacc[mi][dg];
                ushort4 o;
                o.x = f2bf(tot[0] * il);
                o.y = f2bf(tot[1] * il);
                o.z = f2bf(tot[2] * il);
                o.w = f2bf(tot[3] * il);
                *reinterpret_cast<ushort4*>(&av[tok * HID + h * DHEAD + dg * 16 + row_g]) = o;
            }
        }
    }
}

extern "C" void kernel_launch(void* const* d_in, const int* in_sizes, int n_in,
                              void* d_out, int out_size, void* d_ws, size_t ws_size,
                              hipStream_t stream) {
    const float* x     = (const float*)d_in[0];
    const float* W_qkv = (const float*)d_in[1];
    const float* b_qkv = (const float*)d_in[2];
    const float* W_o   = (const float*)d_in[3];
    const float* b_o   = (const float*)d_in[4];
    float* out = (float*)d_out;

    const int n_x    = NTOK * HID;
    const int n_wqkv = QKV_N * HID;
    const int n_wo   = HID * HID;
    const int n_qkv  = NTOK * QKV_N;
    const int n_av   = NTOK * HID;

    short* xb    = (short*)d_ws;
    short* wqkvb = xb + n_x;
    short* wob   = wqkvb + n_wqkv;
    short* qkv   = wob + n_wo;
    short* av    = qkv + n_qkv;
    short* vP    = av + n_av;

    // fused cast: x, W_qkv, W_o in ONE launch (R18 verified)
    cast3_f32_bf16<<<(N1 + N2 + N3) / 256, 256, 0, stream>>>(
        x, W_qkv, W_o, (unsigned short*)xb, (unsigned short*)wqkvb, (unsigned short*)wob);

    // qkv = x @ W_qkv^T + b_qkv  -> bf16 [4096][3072]; BN=128 (verified optimum)
    gemm_bt<128, 2><<<(NTOK / 128) * (QKV_N / 128), 256, 0, stream>>>(
        xb, wqkvb, b_qkv, (void*)qkv, NTOK, QKV_N, HID);

    // vP [32 bh][64 T][64 d][32 j] (PV-fragment order)
    transpose_v<<<dim3(SEQ / 64, BATCH * NHEAD), 256, 0, stream>>>(qkv, vP);

    // attention -> av bf16 [4096][1024]; R13 byte-exact (1024 blocks x 4 waves)
    attn_fwd<<<1024, 256, 0, stream>>>(qkv, vP, av);

    // out = av @ W_o^T + b_o  -> fp32
    gemm_bt<64, 0><<<(NTOK / 128) * (HID / 64), 256, 0, stream>>>(
        av, wob, b_o, (void*)out, NTOK, HID, HID);
}